// Round 3
// baseline (177.491 us; speedup 1.0000x reference)
//
#include <hip/hip_runtime.h>
#include <hip/hip_bf16.h>

// MoE top-1, expert-grouped: N=8192 tokens, D=256, H=64, E=32, fp32.
// Pipeline: memset(counts) -> router -> scan(+tile table) -> scatter -> ffn.
//
// ws layout (ints):
//   [0..32)    counts
//   [32..64)   cursor
//   [64..97)   offsets (33)
//   [128..288) tileExpert (MAX_TILES)
//   [320..480) tileStart
//   [1024..9216)  eidx
//   [9216..17408) perm

constexpr int D = 256;
constexpr int H = 64;
constexpr int E = 32;
constexpr int TPB_R = 32;      // tokens per router block
constexpr int T_TILE = 64;     // tokens per ffn tile
constexpr int MAX_TILES = 160; // 8192/64 + 32 partial tiles

// ---------------- router ----------------
// Bit-exact replication of the passing baseline's summation order:
// per (token, e): 8 partials of 32 k (ascending, fma chain from 0),
// then s = rb[e]; s += partial[p] for p ascending.
__global__ __launch_bounds__(256) void router_kernel(
    const float* __restrict__ x, const float* __restrict__ rw,
    const float* __restrict__ rb, int* __restrict__ ws)
{
    __shared__ float4 xs[TPB_R][66];   // row stride 66 f4 (=264 floats)
    __shared__ float4 rws[E][66];
    __shared__ float logitS[TPB_R][E + 1];

    const int t = threadIdx.x;
    const int n0 = blockIdx.x * TPB_R;

    const float4* x4 = (const float4*)x;
    const float4* rw4 = (const float4*)rw;
    for (int i = t; i < TPB_R * 64; i += 256) {
        int r = i >> 6, q = i & 63;
        xs[r][q] = x4[(size_t)(n0 + r) * 64 + q];
        rws[r][q] = rw4[r * 64 + q];
    }
    __syncthreads();

    const int e = t & 31;
    const int g = t >> 3 >> 2;         // t>>5: 0..7 token group
    float s[4];
#pragma unroll
    for (int j = 0; j < 4; ++j) s[j] = rb[e];
#pragma unroll
    for (int p = 0; p < 8; ++p) {
        float sp[4] = {0.f, 0.f, 0.f, 0.f};
#pragma unroll
        for (int k4 = 0; k4 < 8; ++k4) {
            float4 wv = rws[e][p * 8 + k4];
#pragma unroll
            for (int j = 0; j < 4; ++j) {
                float4 xv = xs[g * 4 + j][p * 8 + k4];
                sp[j] = fmaf(xv.x, wv.x, sp[j]);
                sp[j] = fmaf(xv.y, wv.y, sp[j]);
                sp[j] = fmaf(xv.z, wv.z, sp[j]);
                sp[j] = fmaf(xv.w, wv.w, sp[j]);
            }
        }
#pragma unroll
        for (int j = 0; j < 4; ++j) s[j] += sp[j];
    }
#pragma unroll
    for (int j = 0; j < 4; ++j) logitS[g * 4 + j][e] = s[j];
    __syncthreads();

    if (t < TPB_R) {
        float best = logitS[t][0];
        int bi = 0;
#pragma unroll
        for (int i = 1; i < E; ++i) {
            float v = logitS[t][i];
            if (v > best) { best = v; bi = i; }   // strict > : first occurrence
        }
        ws[1024 + n0 + t] = bi;
        atomicAdd(&ws[bi], 1);
    }
}

// ---------------- scan + tile table ----------------
__global__ void scan_kernel(int* __restrict__ ws)
{
    __shared__ int cts[E];
    __shared__ int offs[E + 1];
    const int t = threadIdx.x;
    if (t < E) cts[t] = ws[t];
    __syncthreads();
    if (t == 0) {
        int off = 0;
        for (int e2 = 0; e2 < E; ++e2) { offs[e2] = off; off += cts[e2]; }
        offs[E] = off;
    }
    __syncthreads();
    if (t < E) { ws[64 + t] = offs[t]; ws[32 + t] = offs[t]; }
    if (t == E) ws[64 + E] = offs[E];
    if (t == 0) {
        int nt = 0;
        for (int e2 = 0; e2 < E; ++e2)
            for (int s2 = 0; s2 < cts[e2]; s2 += T_TILE) {
                ws[128 + nt] = e2;
                ws[320 + nt] = offs[e2] + s2;
                ++nt;
            }
        for (; nt < MAX_TILES; ++nt) ws[128 + nt] = -1;
    }
}

// ---------------- scatter ----------------
__global__ __launch_bounds__(256) void scatter_kernel(int* __restrict__ ws)
{
    const int n = blockIdx.x * 256 + threadIdx.x;
    const int e = ws[1024 + n];
    const int pos = atomicAdd(&ws[32 + e], 1);
    ws[9216 + pos] = n;
}

// ---------------- ffn (per-expert tile) ----------------
// Block: 256 thr = 4 waves; tile = 64 tokens of one expert; lane = token.
// GEMM1: wave w owns h-cols [16w,16w+16); GEMM2: wave w owns out-cols [64w,64w+64).
// Weights read as wave-uniform scalar loads (readfirstlane'd column base).
__global__ __launch_bounds__(256) void ffn_kernel(
    const float* __restrict__ x,
    const float* __restrict__ W1, const float* __restrict__ b1,
    const float* __restrict__ W2, const float* __restrict__ b2,
    const int* __restrict__ ws, float* __restrict__ out)
{
    __shared__ float xsl[T_TILE][260];   // +4 float pad: b128 reads conflict-free
    __shared__ float hsl[T_TILE][68];

    const int b = blockIdx.x;
    const int e = ws[128 + b];
    if (e < 0) return;
    const int start = ws[320 + b];
    const int cnt = min(T_TILE, ws[64 + e + 1] - start);
    const int t = threadIdx.x;
    const int lane = t & 63;
    const int w = t >> 6;
    const int* __restrict__ perm = ws + 9216;

    // stage x tile (gather rows via perm; coalesced float4 per row)
    {
        const float4* x4 = (const float4*)x;
        for (int i = t; i < cnt * 64; i += 256) {
            int r = i >> 6, q = i & 63;
            int row = perm[start + r];
            *(float4*)&xsl[r][q * 4] = x4[(size_t)row * 64 + q];
        }
    }
    __syncthreads();

    const float* w1e = W1 + (size_t)e * (D * H);
    const int c0 = __builtin_amdgcn_readfirstlane(w * 16);

    float acc[16];
#pragma unroll
    for (int j = 0; j < 16; ++j) acc[j] = b1[e * H + c0 + j];
    for (int k4 = 0; k4 < 64; ++k4) {
        float4 xv = *(const float4*)&xsl[lane][k4 * 4];
        const float* r0 = w1e + (k4 * 4 + 0) * H + c0;
        const float* r1 = w1e + (k4 * 4 + 1) * H + c0;
        const float* r2 = w1e + (k4 * 4 + 2) * H + c0;
        const float* r3 = w1e + (k4 * 4 + 3) * H + c0;
#pragma unroll
        for (int j = 0; j < 16; ++j) {
            acc[j] = fmaf(xv.x, r0[j], acc[j]);
            acc[j] = fmaf(xv.y, r1[j], acc[j]);
            acc[j] = fmaf(xv.z, r2[j], acc[j]);
            acc[j] = fmaf(xv.w, r3[j], acc[j]);
        }
    }
#pragma unroll
    for (int j4 = 0; j4 < 4; ++j4) {
        float4 v;
        v.x = fmaxf(acc[j4 * 4 + 0], 0.f);
        v.y = fmaxf(acc[j4 * 4 + 1], 0.f);
        v.z = fmaxf(acc[j4 * 4 + 2], 0.f);
        v.w = fmaxf(acc[j4 * 4 + 3], 0.f);
        *(float4*)&hsl[lane][c0 + j4 * 4] = v;
    }
    __syncthreads();

    const float* w2e = W2 + (size_t)e * (H * D);
    const int d0 = __builtin_amdgcn_readfirstlane(w * 64);

    float acc2[64];
#pragma unroll
    for (int j = 0; j < 64; ++j) acc2[j] = b2[e * D + d0 + j];
    // jc-chunked so scalar weight loads stay within SGPR budget
#pragma unroll
    for (int jc = 0; jc < 4; ++jc) {
        float* a = acc2 + jc * 16;
        const float* wbase = w2e + d0 + jc * 16;
        for (int k4 = 0; k4 < 16; ++k4) {
            float4 hv = *(const float4*)&hsl[lane][k4 * 4];
            const float* r0 = wbase + (k4 * 4 + 0) * D;
            const float* r1 = wbase + (k4 * 4 + 1) * D;
            const float* r2 = wbase + (k4 * 4 + 2) * D;
            const float* r3 = wbase + (k4 * 4 + 3) * D;
#pragma unroll
            for (int j = 0; j < 16; ++j) {
                a[j] = fmaf(hv.x, r0[j], a[j]);
                a[j] = fmaf(hv.y, r1[j], a[j]);
                a[j] = fmaf(hv.z, r2[j], a[j]);
                a[j] = fmaf(hv.w, r3[j], a[j]);
            }
        }
    }

    if (lane < cnt) {
        const int row = perm[start + lane];
        float4* o4 = (float4*)out;
#pragma unroll
        for (int j4 = 0; j4 < 16; ++j4) {
            float4 v;
            v.x = fmaxf(acc2[j4 * 4 + 0], 0.f);
            v.y = fmaxf(acc2[j4 * 4 + 1], 0.f);
            v.z = fmaxf(acc2[j4 * 4 + 2], 0.f);
            v.w = fmaxf(acc2[j4 * 4 + 3], 0.f);
            o4[(size_t)row * 64 + (d0 >> 2) + j4] = v;
        }
    }
}

extern "C" void kernel_launch(void* const* d_in, const int* in_sizes, int n_in,
                              void* d_out, int out_size, void* d_ws, size_t ws_size,
                              hipStream_t stream) {
    const float* x  = (const float*)d_in[0];
    const float* rw = (const float*)d_in[1];
    const float* rb = (const float*)d_in[2];
    const float* W1 = (const float*)d_in[3];
    const float* b1 = (const float*)d_in[4];
    const float* W2 = (const float*)d_in[5];
    const float* b2 = (const float*)d_in[6];
    float* out = (float*)d_out;
    int* ws = (int*)d_ws;

    const int N = in_sizes[0] / D;   // 8192 tokens

    hipMemsetAsync(ws, 0, 128, stream);                       // counts = 0
    router_kernel<<<N / TPB_R, 256, 0, stream>>>(x, rw, rb, ws);
    scan_kernel<<<1, 256, 0, stream>>>(ws);
    scatter_kernel<<<N / 256, 256, 0, stream>>>(ws);
    ffn_kernel<<<MAX_TILES, 256, 0, stream>>>(x, W1, b1, W2, b2, ws, out);
}

// Round 5
// 115.113 us; speedup vs baseline: 1.5419x; 1.5419x over previous
//
#include <hip/hip_runtime.h>
#include <hip/hip_bf16.h>

// MoE top-1, expert-grouped, register-stationary FFN weights.
// N=8192 tokens, D=256, H=64, E=32, fp32 (no fp32 MFMA on CDNA4 -> VALU).
// Pipeline: memset(64 ints) -> router(256 blk) -> scatter(32 blk)
//           -> ffn(544 blk, 16-token tiles, self-locating from counts).
//
// ws ints: [0..32) counts | [32..64) cursors | [64..8256) eidx
//          | [8256..16448) perm     (65.8 KB total)

constexpr int D = 256;
constexpr int H = 64;
constexpr int E = 32;
constexpr int T_TILE = 16;
constexpr int MAX_TILES = 544;   // sum ceil(c_e/16) <= 512+30
constexpr int EIDX = 64;
constexpr int PERM = 8256;

__device__ __forceinline__ float quad_reduce(float v) {
    // sum across the 4 lanes of each quad via DPP quad_perm (VALU-only)
    int i1 = __builtin_bit_cast(int, v);
    v += __builtin_bit_cast(float,
        __builtin_amdgcn_mov_dpp(i1, 0xB1, 0xF, 0xF, true));   // [1,0,3,2]
    int i2 = __builtin_bit_cast(int, v);
    v += __builtin_bit_cast(float,
        __builtin_amdgcn_mov_dpp(i2, 0x4E, 0xF, 0xF, true));   // [2,3,0,1]
    return v;
}

// ---------------- router ----------------
// EXACT round-3 compute (passed: bit-exact argmax vs baseline order):
// per (token,e): s = rb[e]; for p<8: sp = fma chain over 32 ascending k;
// s += sp.  Block = 32 tokens, 256 thr: thread (e = t&31, g = t>>5) does
// 4 tokens. Plus: LDS histogram -> 1 global atomicAdd per expert per block.
__global__ __launch_bounds__(256) void router_kernel(
    const float* __restrict__ x, const float* __restrict__ rw,
    const float* __restrict__ rb, int* __restrict__ ws)
{
    __shared__ float4 xs[32][66];
    __shared__ float4 rws[E][66];
    __shared__ float logitS[32][E + 1];
    __shared__ int lcnt[E];

    const int t = threadIdx.x;
    const int n0 = blockIdx.x * 32;
    if (t < E) lcnt[t] = 0;

    const float4* x4 = (const float4*)x;
    const float4* rw4 = (const float4*)rw;
    for (int i = t; i < 32 * 64; i += 256) {
        int r = i >> 6, q = i & 63;
        xs[r][q] = x4[(size_t)(n0 + r) * 64 + q];
        rws[r][q] = rw4[r * 64 + q];
    }
    __syncthreads();

    {
        const int e = t & 31, g = t >> 5;
        float s[4];
#pragma unroll
        for (int j = 0; j < 4; ++j) s[j] = rb[e];
#pragma unroll
        for (int p = 0; p < 8; ++p) {
            float sp[4] = {0.f, 0.f, 0.f, 0.f};
#pragma unroll
            for (int k4 = 0; k4 < 8; ++k4) {
                float4 wv = rws[e][p * 8 + k4];
#pragma unroll
                for (int j = 0; j < 4; ++j) {
                    float4 xv = xs[g * 4 + j][p * 8 + k4];
                    sp[j] = fmaf(xv.x, wv.x, sp[j]);
                    sp[j] = fmaf(xv.y, wv.y, sp[j]);
                    sp[j] = fmaf(xv.z, wv.z, sp[j]);
                    sp[j] = fmaf(xv.w, wv.w, sp[j]);
                }
            }
#pragma unroll
            for (int j = 0; j < 4; ++j) s[j] += sp[j];
        }
#pragma unroll
        for (int j = 0; j < 4; ++j) logitS[g * 4 + j][e] = s[j];
    }
    __syncthreads();

    if (t < 32) {
        float best = logitS[t][0];
        int bi = 0;
#pragma unroll
        for (int i = 1; i < E; ++i) {
            float v = logitS[t][i];
            if (v > best) { best = v; bi = i; }   // strict >: first occurrence
        }
        ws[EIDX + n0 + t] = bi;
        atomicAdd(&lcnt[bi], 1);
    }
    __syncthreads();
    if (t < E && lcnt[t] > 0) atomicAdd(&ws[t], lcnt[t]);
}

// ---------------- scatter ----------------
// Block = 256 tokens. LDS rank + per-block range reservation:
// pos = offs[e] + block_base_e + local_rank. No per-token global atomics.
__global__ __launch_bounds__(256) void scatter_kernel(int* __restrict__ ws)
{
    __shared__ int lcnt[E], lbase[E], offs_s[E], cnts[E];
    const int t = threadIdx.x;
    const int n = blockIdx.x * 256 + t;
    if (t < E) { lcnt[t] = 0; cnts[t] = ws[t]; }
    __syncthreads();
    const int e = ws[EIDX + n];
    const int rank = atomicAdd(&lcnt[e], 1);      // LDS atomic
    __syncthreads();
    if (t < E) {
        int o = 0;
        for (int i = 0; i < E; ++i) if (i < t) o += cnts[i];
        offs_s[t] = o;
        if (lcnt[t] > 0) lbase[t] = atomicAdd(&ws[32 + t], lcnt[t]);
    }
    __syncthreads();
    ws[PERM + offs_s[e] + lbase[e] + rank] = n;
}

// ---------------- ffn ----------------
// Block: 16-token tile of one expert, 256 thr (4 waves), self-locating.
// lane = s + 4*q (s=lane&3, q=lane>>2).
// GEMM1: wave w = k-range [64w,64w+64); thread k-slice (4w+s)*16..+16,
//        4 h-cols {q+16j}; 64 W1 regs; quad DPP-reduce; partial -> LDS.
// GEMM2: wave w = d-range [64w,64w+64); thread h-slice [16s,16s+16),
//        4 d-cols {64w+q+16j}; 64 W2 regs; hs from LDS.
__global__ __launch_bounds__(256) void ffn_kernel(
    const float* __restrict__ x,
    const float* __restrict__ W1, const float* __restrict__ b1,
    const float* __restrict__ W2, const float* __restrict__ b2,
    const int* __restrict__ ws, float* __restrict__ out)
{
    __shared__ float part[4][T_TILE][H];   // 16 KB
    __shared__ float hsl[T_TILE][H];       // 4 KB
    __shared__ int rowsl[T_TILE];
    __shared__ int cs[E];
    __shared__ int info[3];                // e, start, cnt

    const int t = threadIdx.x;
    if (t < E) cs[t] = ws[t];
    __syncthreads();
    if (t == 0) {
        int b = blockIdx.x, off = 0, te = -1, tst = 0, tc = 0;
        for (int e2 = 0; e2 < E; ++e2) {
            const int c = cs[e2];
            const int nt = (c + T_TILE - 1) >> 4;
            if (b < nt) { te = e2; tst = off + b * T_TILE;
                          tc = min(T_TILE, c - b * T_TILE); break; }
            b -= nt; off += c;
        }
        info[0] = te; info[1] = tst; info[2] = tc;
    }
    __syncthreads();
    const int e = info[0];
    if (e < 0) return;
    const int start = info[1];
    const int cnt = info[2];
    const int lane = t & 63;
    const int w = t >> 6;
    const int s = lane & 3;
    const int q = lane >> 2;

    if (t < T_TILE)
        rowsl[t] = ws[PERM + start + (t < cnt ? t : 0)];

    // W1 fragment -> 64 VGPRs (each block reads W1[e] exactly once)
    const float* w1e = W1 + (size_t)e * (D * H);
    float w1r[64];
    {
        const float* base = w1e + (w * 4 + s) * 16 * H + q;
#pragma unroll
        for (int j = 0; j < 4; ++j)
#pragma unroll
            for (int k = 0; k < 16; ++k)
                w1r[j * 16 + k] = base[k * H + 16 * j];
    }
    __syncthreads();

#define LOADX(buf, row) {                                                  \
        const float* xb_ = x + (size_t)(row) * D + (w * 4 + s) * 16;       \
        buf[0] = *(const float4*)(xb_ + 0);                                \
        buf[1] = *(const float4*)(xb_ + 4);                                \
        buf[2] = *(const float4*)(xb_ + 8);                                \
        buf[3] = *(const float4*)(xb_ + 12); }

#define BODY1(tok, xb) {                                                   \
        float sp0 = 0.f, sp1 = 0.f, sp2 = 0.f, sp3 = 0.f;                  \
        _Pragma("unroll")                                                  \
        for (int k4 = 0; k4 < 4; ++k4) {                                   \
            float4 xv = xb[k4];                                            \
            _Pragma("unroll")                                              \
            for (int m = 0; m < 4; ++m) {                                  \
                const int k = k4 * 4 + m;                                  \
                const float xs_ = (m == 0) ? xv.x : (m == 1) ? xv.y        \
                                 : (m == 2) ? xv.z : xv.w;                 \
                sp0 = fmaf(xs_, w1r[0 * 16 + k], sp0);                     \
                sp1 = fmaf(xs_, w1r[1 * 16 + k], sp1);                     \
                sp2 = fmaf(xs_, w1r[2 * 16 + k], sp2);                     \
                sp3 = fmaf(xs_, w1r[3 * 16 + k], sp3);                     \
            }                                                              \
        }                                                                  \
        sp0 = quad_reduce(sp0); sp1 = quad_reduce(sp1);                    \
        sp2 = quad_reduce(sp2); sp3 = quad_reduce(sp3);                    \
        float a_ = (s & 1) ? sp1 : sp0;                                    \
        float c_ = (s & 1) ? sp3 : sp2;                                    \
        part[w][tok][q + 16 * s] = (s & 2) ? c_ : a_; }

    {
        float4 xa[4], xb4[4];
        LOADX(xa, rowsl[0]);
        for (int tok = 0; tok < cnt; tok += 2) {
            if (tok + 1 < cnt) LOADX(xb4, rowsl[tok + 1]);
            BODY1(tok, xa);
            if (tok + 1 < cnt) {
                if (tok + 2 < cnt) LOADX(xa, rowsl[tok + 2]);
                BODY1(tok + 1, xb4);
            }
        }
    }

    // W2 fragment loads issued here: overlap barrier + relu phase
    const float* w2e = W2 + (size_t)e * (H * D);
    float w2r[64];
    {
        const float* base = w2e + 16 * s * D + 64 * w + q;
#pragma unroll
        for (int j = 0; j < 4; ++j)
#pragma unroll
            for (int k = 0; k < 16; ++k)
                w2r[j * 16 + k] = base[k * D + 16 * j];
    }
    const float b2v = b2[e * D + 64 * w + q + 16 * s];
    __syncthreads();

    // cross-wave reduce + bias + relu -> hsl
    {
        const int h = t & 63;
        const int tq = t >> 6;
        const float b1v = b1[e * H + h];
#pragma unroll
        for (int r = 0; r < 4; ++r) {
            const int tok = tq * 4 + r;
            if (tok < cnt) {
                float v = part[0][tok][h] + part[1][tok][h]
                        + part[2][tok][h] + part[3][tok][h] + b1v;
                hsl[tok][h] = fmaxf(v, 0.f);
            }
        }
    }
    __syncthreads();

#define LOADH(buf, tok) {                                                  \
        const float* hb_ = &hsl[tok][s * 16];                              \
        buf[0] = *(const float4*)(hb_ + 0);                                \
        buf[1] = *(const float4*)(hb_ + 4);                                \
        buf[2] = *(const float4*)(hb_ + 8);                                \
        buf[3] = *(const float4*)(hb_ + 12); }

#define BODY2(tok, hb) {                                                   \
        float sp0 = 0.f, sp1 = 0.f, sp2 = 0.f, sp3 = 0.f;                  \
        _Pragma("unroll")                                                  \
        for (int k4 = 0; k4 < 4; ++k4) {                                   \
            float4 hv = hb[k4];                                            \
            _Pragma("unroll")                                              \
            for (int m = 0; m < 4; ++m) {                                  \
                const int k = k4 * 4 + m;                                  \
                const float hs_ = (m == 0) ? hv.x : (m == 1) ? hv.y        \
                                 : (m == 2) ? hv.z : hv.w;                 \
                sp0 = fmaf(hs_, w2r[0 * 16 + k], sp0);                     \
                sp1 = fmaf(hs_, w2r[1 * 16 + k], sp1);                     \
                sp2 = fmaf(hs_, w2r[2 * 16 + k], sp2);                     \
                sp3 = fmaf(hs_, w2r[3 * 16 + k], sp3);                     \
            }                                                              \
        }                                                                  \
        sp0 = quad_reduce(sp0); sp1 = quad_reduce(sp1);                    \
        sp2 = quad_reduce(sp2); sp3 = quad_reduce(sp3);                    \
        float a_ = (s & 1) ? sp1 : sp0;                                    \
        float c_ = (s & 1) ? sp3 : sp2;                                    \
        const float val_ = ((s & 2) ? c_ : a_) + b2v;                      \
        const int row_ = rowsl[tok];                                       \
        out[(size_t)row_ * D + 64 * w + q + 16 * s] = fmaxf(val_, 0.f); }

    {
        float4 ha[4], hb4[4];
        LOADH(ha, 0);
        for (int tok = 0; tok < cnt; tok += 2) {
            if (tok + 1 < cnt) LOADH(hb4, tok + 1);
            BODY2(tok, ha);
            if (tok + 1 < cnt) {
                if (tok + 2 < cnt) LOADH(ha, tok + 2);
                BODY2(tok + 1, hb4);
            }
        }
    }
#undef LOADX
#undef BODY1
#undef LOADH
#undef BODY2
}

extern "C" void kernel_launch(void* const* d_in, const int* in_sizes, int n_in,
                              void* d_out, int out_size, void* d_ws, size_t ws_size,
                              hipStream_t stream) {
    const float* x  = (const float*)d_in[0];
    const float* rw = (const float*)d_in[1];
    const float* rb = (const float*)d_in[2];
    const float* W1 = (const float*)d_in[3];
    const float* b1 = (const float*)d_in[4];
    const float* W2 = (const float*)d_in[5];
    const float* b2 = (const float*)d_in[6];
    float* out = (float*)d_out;
    int* ws = (int*)d_ws;

    const int N = in_sizes[0] / D;   // 8192

    hipMemsetAsync(ws, 0, 256, stream);             // counts + cursors
    router_kernel<<<N / 32, 256, 0, stream>>>(x, rw, rb, ws);
    scatter_kernel<<<N / 256, 256, 0, stream>>>(ws);
    ffn_kernel<<<MAX_TILES, 256, 0, stream>>>(x, W1, b1, W2, b2, ws, out);
}

// Round 8
// 111.204 us; speedup vs baseline: 1.5961x; 1.0351x over previous
//
#include <hip/hip_runtime.h>
#include <hip/hip_bf16.h>

// MoE top-1, expert-grouped, zero global atomics.
// N=8192 tokens, D=256, H=64, E=32, fp32 (no fp32 MFMA on CDNA4 -> VALU).
// Pipeline: router(256 blk: eidx + private hist row)
//        -> scatter(32 blk: hist prefix -> perm, counts)
//        -> ffn(544 blk, 16-token tiles, self-locating from counts).
// No memset (hist rows fully overwritten every run).
//
// ws ints: hist[256][32] @0 | eidx[8192] @8192 | perm[8192] @16384
//          | counts[32] @24576   (~98 KB)

constexpr int D = 256;
constexpr int H = 64;
constexpr int E = 32;
constexpr int T_TILE = 16;
constexpr int MAX_TILES = 544;   // sum ceil(c_e/16) <= 543
constexpr int HIST = 0;
constexpr int EIDX = 8192;
constexpr int PERM = 16384;
constexpr int WCNT = 24576;

__device__ __forceinline__ float quad_reduce(float v) {
    // sum across the 4 lanes of each quad via DPP quad_perm (VALU-only)
    int i1 = __builtin_bit_cast(int, v);
    v += __builtin_bit_cast(float,
        __builtin_amdgcn_mov_dpp(i1, 0xB1, 0xF, 0xF, true));   // [1,0,3,2]
    int i2 = __builtin_bit_cast(int, v);
    v += __builtin_bit_cast(float,
        __builtin_amdgcn_mov_dpp(i2, 0x4E, 0xF, 0xF, true));   // [2,3,0,1]
    return v;
}

// ---------------- router ----------------
// Round-5 compute, bit-exact chains: per (token,e): s = rb[e];
// for p<8: sp = fma chain over 32 ascending k; s += sp.
// rw staged TRANSPOSED rwt[k4][e] -> lane-contiguous conflict-free reads
// (old [E][66] layout was an 8-way bank conflict on lane-varying e).
// Outputs: eidx per token + non-atomic private hist row. No global atomics.
__global__ __launch_bounds__(256) void router_kernel(
    const float* __restrict__ x, const float* __restrict__ rw,
    const float* __restrict__ rb, int* __restrict__ ws)
{
    __shared__ float4 xs[32][65];
    __shared__ float4 rwt[64][33];     // [k4][e], padded
    __shared__ float logitS[32][E + 1];
    __shared__ int lcnt[E];

    const int t = threadIdx.x;
    const int n0 = blockIdx.x * 32;
    if (t < E) lcnt[t] = 0;

    const float4* x4 = (const float4*)x;
    const float4* rw4 = (const float4*)rw;
    for (int i = t; i < 32 * 64; i += 256) {
        int r = i >> 6, q = i & 63;
        xs[r][q] = x4[(size_t)(n0 + r) * 64 + q];
        rwt[q][r] = rw4[i];            // i = r*64+q : coalesced global read
    }
    __syncthreads();

    {
        const int e = t & 31, g = t >> 5;
        float s[4];
#pragma unroll
        for (int j = 0; j < 4; ++j) s[j] = rb[e];
#pragma unroll
        for (int p = 0; p < 8; ++p) {
            float sp[4] = {0.f, 0.f, 0.f, 0.f};
#pragma unroll
            for (int k4 = 0; k4 < 8; ++k4) {
                float4 wv = rwt[p * 8 + k4][e];
#pragma unroll
                for (int j = 0; j < 4; ++j) {
                    float4 xv = xs[g * 4 + j][p * 8 + k4];
                    sp[j] = fmaf(xv.x, wv.x, sp[j]);
                    sp[j] = fmaf(xv.y, wv.y, sp[j]);
                    sp[j] = fmaf(xv.z, wv.z, sp[j]);
                    sp[j] = fmaf(xv.w, wv.w, sp[j]);
                }
            }
#pragma unroll
            for (int j = 0; j < 4; ++j) s[j] += sp[j];
        }
#pragma unroll
        for (int j = 0; j < 4; ++j) logitS[g * 4 + j][e] = s[j];
    }
    __syncthreads();

    if (t < 32) {
        float best = logitS[t][0];
        int bi = 0;
#pragma unroll
        for (int i = 1; i < E; ++i) {
            float v = logitS[t][i];
            if (v > best) { best = v; bi = i; }   // strict >: first occurrence
        }
        ws[EIDX + n0 + t] = bi;
        atomicAdd(&lcnt[bi], 1);                  // LDS atomic only
    }
    __syncthreads();
    if (t < E) ws[HIST + blockIdx.x * E + t] = lcnt[t];   // private row
}

// ---------------- scatter ----------------
// Block b owns tokens [256b, 256b+256) = hist rows [8b, 8b+8).
// Recomputes column sums (all 256 rows) + "below this block" prefix from
// hist (coalesced 128B rows, L2-hot), ranks its tokens via LDS atomics.
// perm order within an expert is arbitrary -> any interleave is correct.
__global__ __launch_bounds__(256) void scatter_kernel(int* __restrict__ ws)
{
    __shared__ int cfull[8][E], cbelow[8][E];
    __shared__ int cnts_s[E], below_s[E], offs_s[E], lcnt[E];

    const int t = threadIdx.x;
    const int b = blockIdx.x;
    const int c = t >> 5, e = t & 31;             // 8 chunks x 32 rows
    const int rlim = 8 * b;

    int full = 0, below = 0;
    for (int i = 0; i < 32; ++i) {
        const int r = c * 32 + i;
        const int v = ws[HIST + r * E + e];       // coalesced
        full += v;
        if (r < rlim) below += v;
    }
    cfull[c][e] = full; cbelow[c][e] = below;
    __syncthreads();
    if (t < E) {
        int tot = 0, bg = 0;
#pragma unroll
        for (int c2 = 0; c2 < 8; ++c2) { tot += cfull[c2][t]; bg += cbelow[c2][t]; }
        cnts_s[t] = tot; below_s[t] = bg; lcnt[t] = 0;
    }
    __syncthreads();
    if (t == 0) {
        int off = 0;
        for (int e2 = 0; e2 < E; ++e2) { offs_s[e2] = off; off += cnts_s[e2]; }
    }
    __syncthreads();
    {
        const int n = b * 256 + t;
        const int e2 = ws[EIDX + n];
        const int r = atomicAdd(&lcnt[e2], 1);    // LDS atomic
        ws[PERM + offs_s[e2] + below_s[e2] + r] = n;
    }
    if (b == 0 && t < E) ws[WCNT + t] = cnts_s[t];
}

// ---------------- ffn (round-5 core, verified) ----------------
// Block: 16-token tile of one expert, 256 thr (4 waves), self-locating.
// lane = s + 4*q (s=lane&3, q=lane>>2).
// GEMM1: wave w = k-range [64w,64w+64); thread k-slice (4w+s)*16..+16,
//        4 h-cols {q+16j}; 64 W1 regs; quad DPP-reduce; partial -> LDS.
// GEMM2: wave w = d-range [64w,64w+64); thread h-slice [16s,16s+16),
//        4 d-cols {64w+q+16j}; 64 W2 regs; hs from LDS.
__global__ __launch_bounds__(256) void ffn_kernel(
    const float* __restrict__ x,
    const float* __restrict__ W1, const float* __restrict__ b1,
    const float* __restrict__ W2, const float* __restrict__ b2,
    const int* __restrict__ ws, float* __restrict__ out)
{
    __shared__ float part[4][T_TILE][H];   // 16 KB
    __shared__ float hsl[T_TILE][H];       // 4 KB
    __shared__ int rowsl[T_TILE];
    __shared__ int cs[E];
    __shared__ int info[3];                // e, start, cnt

    const int t = threadIdx.x;
    if (t < E) cs[t] = ws[WCNT + t];
    __syncthreads();
    if (t == 0) {
        int b = blockIdx.x, off = 0, te = -1, tst = 0, tc = 0;
        for (int e2 = 0; e2 < E; ++e2) {
            const int c = cs[e2];
            const int nt = (c + T_TILE - 1) >> 4;
            if (b < nt) { te = e2; tst = off + b * T_TILE;
                          tc = min(T_TILE, c - b * T_TILE); break; }
            b -= nt; off += c;
        }
        info[0] = te; info[1] = tst; info[2] = tc;
    }
    __syncthreads();
    const int e = info[0];
    if (e < 0) return;
    const int start = info[1];
    const int cnt = info[2];
    const int lane = t & 63;
    const int w = t >> 6;
    const int s = lane & 3;
    const int q = lane >> 2;

    if (t < T_TILE)
        rowsl[t] = ws[PERM + start + (t < cnt ? t : 0)];

    // W1 fragment -> 64 VGPRs (each block reads W1[e] exactly once)
    const float* w1e = W1 + (size_t)e * (D * H);
    float w1r[64];
    {
        const float* base = w1e + (w * 4 + s) * 16 * H + q;
#pragma unroll
        for (int j = 0; j < 4; ++j)
#pragma unroll
            for (int k = 0; k < 16; ++k)
                w1r[j * 16 + k] = base[k * H + 16 * j];
    }
    __syncthreads();

#define LOADX(buf, row) {                                                  \
        const float* xb_ = x + (size_t)(row) * D + (w * 4 + s) * 16;       \
        buf[0] = *(const float4*)(xb_ + 0);                                \
        buf[1] = *(const float4*)(xb_ + 4);                                \
        buf[2] = *(const float4*)(xb_ + 8);                                \
        buf[3] = *(const float4*)(xb_ + 12); }

#define BODY1(tok, xb) {                                                   \
        float sp0 = 0.f, sp1 = 0.f, sp2 = 0.f, sp3 = 0.f;                  \
        _Pragma("unroll")                                                  \
        for (int k4 = 0; k4 < 4; ++k4) {                                   \
            float4 xv = xb[k4];                                            \
            _Pragma("unroll")                                              \
            for (int m = 0; m < 4; ++m) {                                  \
                const int k = k4 * 4 + m;                                  \
                const float xs_ = (m == 0) ? xv.x : (m == 1) ? xv.y        \
                                 : (m == 2) ? xv.z : xv.w;                 \
                sp0 = fmaf(xs_, w1r[0 * 16 + k], sp0);                     \
                sp1 = fmaf(xs_, w1r[1 * 16 + k], sp1);                     \
                sp2 = fmaf(xs_, w1r[2 * 16 + k], sp2);                     \
                sp3 = fmaf(xs_, w1r[3 * 16 + k], sp3);                     \
            }                                                              \
        }                                                                  \
        sp0 = quad_reduce(sp0); sp1 = quad_reduce(sp1);                    \
        sp2 = quad_reduce(sp2); sp3 = quad_reduce(sp3);                    \
        float a_ = (s & 1) ? sp1 : sp0;                                    \
        float c_ = (s & 1) ? sp3 : sp2;                                    \
        part[w][tok][q + 16 * s] = (s & 2) ? c_ : a_; }

    {
        float4 xa[4], xb4[4];
        LOADX(xa, rowsl[0]);
        for (int tok = 0; tok < cnt; tok += 2) {
            if (tok + 1 < cnt) LOADX(xb4, rowsl[tok + 1]);
            BODY1(tok, xa);
            if (tok + 1 < cnt) {
                if (tok + 2 < cnt) LOADX(xa, rowsl[tok + 2]);
                BODY1(tok + 1, xb4);
            }
        }
    }

    // W2 fragment loads issued here: overlap barrier + relu phase
    const float* w2e = W2 + (size_t)e * (H * D);
    float w2r[64];
    {
        const float* base = w2e + 16 * s * D + 64 * w + q;
#pragma unroll
        for (int j = 0; j < 4; ++j)
#pragma unroll
            for (int k = 0; k < 16; ++k)
                w2r[j * 16 + k] = base[k * D + 16 * j];
    }
    const float b2v = b2[e * D + 64 * w + q + 16 * s];
    __syncthreads();

    // cross-wave reduce + bias + relu -> hsl
    {
        const int h = t & 63;
        const int tq = t >> 6;
        const float b1v = b1[e * H + h];
#pragma unroll
        for (int r = 0; r < 4; ++r) {
            const int tok = tq * 4 + r;
            if (tok < cnt) {
                float v = part[0][tok][h] + part[1][tok][h]
                        + part[2][tok][h] + part[3][tok][h] + b1v;
                hsl[tok][h] = fmaxf(v, 0.f);
            }
        }
    }
    __syncthreads();

#define LOADH(buf, tok) {                                                  \
        const float* hb_ = &hsl[tok][s * 16];                              \
        buf[0] = *(const float4*)(hb_ + 0);                                \
        buf[1] = *(const float4*)(hb_ + 4);                                \
        buf[2] = *(const float4*)(hb_ + 8);                                \
        buf[3] = *(const float4*)(hb_ + 12); }

#define BODY2(tok, hb) {                                                   \
        float sp0 = 0.f, sp1 = 0.f, sp2 = 0.f, sp3 = 0.f;                  \
        _Pragma("unroll")                                                  \
        for (int k4 = 0; k4 < 4; ++k4) {                                   \
            float4 hv = hb[k4];                                            \
            _Pragma("unroll")                                              \
            for (int m = 0; m < 4; ++m) {                                  \
                const int k = k4 * 4 + m;                                  \
                const float hs_ = (m == 0) ? hv.x : (m == 1) ? hv.y        \
                                 : (m == 2) ? hv.z : hv.w;                 \
                sp0 = fmaf(hs_, w2r[0 * 16 + k], sp0);                     \
                sp1 = fmaf(hs_, w2r[1 * 16 + k], sp1);                     \
                sp2 = fmaf(hs_, w2r[2 * 16 + k], sp2);                     \
                sp3 = fmaf(hs_, w2r[3 * 16 + k], sp3);                     \
            }                                                              \
        }                                                                  \
        sp0 = quad_reduce(sp0); sp1 = quad_reduce(sp1);                    \
        sp2 = quad_reduce(sp2); sp3 = quad_reduce(sp3);                    \
        float a_ = (s & 1) ? sp1 : sp0;                                    \
        float c_ = (s & 1) ? sp3 : sp2;                                    \
        const float val_ = ((s & 2) ? c_ : a_) + b2v;                      \
        const int row_ = rowsl[tok];                                       \
        out[(size_t)row_ * D + 64 * w + q + 16 * s] = fmaxf(val_, 0.f); }

    {
        float4 ha[4], hb4[4];
        LOADH(ha, 0);
        for (int tok = 0; tok < cnt; tok += 2) {
            if (tok + 1 < cnt) LOADH(hb4, tok + 1);
            BODY2(tok, ha);
            if (tok + 1 < cnt) {
                if (tok + 2 < cnt) LOADH(ha, tok + 2);
                BODY2(tok + 1, hb4);
            }
        }
    }
#undef LOADX
#undef BODY1
#undef LOADH
#undef BODY2
}

extern "C" void kernel_launch(void* const* d_in, const int* in_sizes, int n_in,
                              void* d_out, int out_size, void* d_ws, size_t ws_size,
                              hipStream_t stream) {
    const float* x  = (const float*)d_in[0];
    const float* rw = (const float*)d_in[1];
    const float* rb = (const float*)d_in[2];
    const float* W1 = (const float*)d_in[3];
    const float* b1 = (const float*)d_in[4];
    const float* W2 = (const float*)d_in[5];
    const float* b2 = (const float*)d_in[6];
    float* out = (float*)d_out;
    int* ws = (int*)d_ws;

    const int N = in_sizes[0] / D;   // 8192

    router_kernel<<<N / 32, 256, 0, stream>>>(x, rw, rb, ws);
    scatter_kernel<<<N / 256, 256, 0, stream>>>(ws);
    ffn_kernel<<<MAX_TILES, 256, 0, stream>>>(x, W1, b1, W2, b2, ws, out);
}